// Round 4
// baseline (36.056 us; speedup 1.0000x reference)
//
#include <hip/hip_runtime.h>
#include <math.h>

#define N_RAYS 86400
#define N_SAMP 287
#define GRP_W  16          // lanes per ray (4 rays per wave)
#define N_CHUNK ((N_SAMP + GRP_W - 1) / GRP_W)   // 18
#define LOG2E 1.4426950408889634f
#define N_CELLS (200 * 200 * 16)   // 640000
#define PLANE   (200 * 16)         // cells per x-plane

// DPP row_shr:N prefix-shift within the 16-lane row; lanes that would read
// below the row edge get `old` (we pass the multiplicative identity 1.0f).
#define ROW_SHR_OLD1(x, N)                                                   \
    __int_as_float(__builtin_amdgcn_update_dpp(                              \
        0x3f800000 /*1.0f*/, __float_as_int(x), 0x110 | (N), 0xF, 0xF, false))

// ds_swizzle BitMode: new_lane = ((lane & and) | or) ^ xor  (per 32-lane half)
#define SWZ(x, pat) __int_as_float(__builtin_amdgcn_ds_swizzle(__float_as_int(x), (pat)))
#define SWZ_BCAST15 0x1F0   // lane 15 of each 16-group
#define SWZ_XOR(m)  (((m) << 10) | 0x1F)

// Prepass: quad[cell(x,y,z)] = { v(x,y,z), v(x,y,z+1~), v(x,y+1~,z), v(x,y+1~,z+1~) }
// (~ = clamped; clamped cells are never consumed as interpolation bases anyway)
__global__ __launch_bounds__(256) void pack_quad_kernel(
    const float* __restrict__ v, float4* __restrict__ q)
{
    int idx = blockIdx.x * blockDim.x + threadIdx.x;
    if (idx >= N_CELLS) return;
    int z  = idx & 15;
    int xy = idx >> 4;
    int y  = xy % 200;
    float a = v[idx];
    float b = (z < 15) ? v[idx + 1]  : a;
    float c, d;
    if (y < 199) {
        c = v[idx + 16];
        d = (z < 15) ? v[idx + 17] : c;
    } else {
        c = a; d = b;
    }
    q[idx] = make_float4(a, b, c, d);
}

__global__ __launch_bounds__(256) void nerf_depth_kernel(
    const float* __restrict__ rays_o,
    const float* __restrict__ rays_d,
    const float4* __restrict__ quad,
    float* __restrict__ depth_out,
    float stepf, float delta)
{
    const int lane = threadIdx.x & 63;
    const int sub  = lane & (GRP_W - 1);
    const int grp  = lane >> 4;
    const int wave = (blockIdx.x * blockDim.x + threadIdx.x) >> 6;
    const int ray  = wave * 4 + grp;         // 86400 = 4 * 21600, exact

    const float ox = rays_o[3*ray+0], oy = rays_o[3*ray+1], oz = rays_o[3*ray+2];
    const float dx = rays_d[3*ray+0], dy = rays_d[3*ray+1], dz = rays_d[3*ray+2];

    const float cx1 = 199.0f / 80.0f;                  const float cx0 = 40.0f * cx1;
    const float cz1 = 15.0f / (5.4f - (-1.0f));        const float cz0 = 1.0f * cz1;
    const float negdelta = -delta;

    float T = 1.0f;
    float depth_acc = 0.0f;
    bool  done = false;

    for (int c = 0; c < N_CHUNK; ++c) {
        const int  s     = c * GRP_W + sub;
        const bool valid = (s < N_SAMP);
        const float z  = __fmul_rn(stepf, (float)s);
        // mask must stay bit-exact vs numpy: separate mul + add, strict compares
        const float px = __fadd_rn(ox, __fmul_rn(dx, z));
        const float py = __fadd_rn(oy, __fmul_rn(dy, z));
        const float pz = __fadd_rn(oz, __fmul_rn(dz, z));
        const bool inside = !((fmaxf(fabsf(px), fabsf(py)) > 40.0f) |
                              (pz < -1.0f) | (pz > 5.4f));
        const bool inb = (!done) && valid && inside;

        const unsigned long long bal = __ballot(inb);
        if (((unsigned)(bal >> (grp * GRP_W)) & 0xFFFFu) == 0u) done = true;
        if (__all(done)) break;

        float alpha = 0.0f, az = 0.0f;
        if (inb) {
            float ix = fminf(fmaxf(__builtin_fmaf(px, cx1, cx0), 0.0f), 199.0f);
            float iy = fminf(fmaxf(__builtin_fmaf(py, cx1, cx0), 0.0f), 199.0f);
            float iz = fminf(fmaxf(__builtin_fmaf(pz, cz1, cz0), 0.0f), 15.0f);
            int x0 = min((int)ix, 198);
            int y0 = min((int)iy, 198);
            int z0 = min((int)iz, 14);
            float fx = ix - (float)x0;
            float fy = iy - (float)y0;
            float fz = iz - (float)z0;
            // all 8 corners via 2 float4 gathers (yz-quad packed layout)
            int cell = (x0 * 200 + y0) * 16 + z0;
            float4 q0 = quad[cell];           // x0-plane
            float4 q1 = quad[cell + PLANE];   // (x0+1)-plane
            float c00 = q0.x + fz * (q0.y - q0.x);
            float c01 = q0.z + fz * (q0.w - q0.z);
            float c10 = q1.x + fz * (q1.y - q1.x);
            float c11 = q1.z + fz * (q1.w - q1.z);
            float c0  = c00 + fy * (c01 - c00);
            float c1  = c10 + fy * (c11 - c10);
            float d   = c0  + fx * (c1  - c0);
            // alpha = 1 - exp(-delta*softplus(d)) = 1 - 2^(-delta*log2(1+e^d))
            float e2 = exp2f(d * LOG2E);
            float lg = __log2f(1.0f + e2);
            alpha = 1.0f - exp2f(negdelta * lg);
            az = alpha * z;
        }

        float g = fmaxf(1.0f - alpha, 1e-10f);

        // 16-lane inclusive prefix product via DPP row_shr
        float P = g;
        P *= ROW_SHR_OLD1(P, 1);
        P *= ROW_SHR_OLD1(P, 2);
        P *= ROW_SHR_OLD1(P, 4);
        P *= ROW_SHR_OLD1(P, 8);
        float E = ROW_SHR_OLD1(P, 1);      // exclusive prefix (lane0 -> 1.0)

        depth_acc = __builtin_fmaf(az, T * E, depth_acc);
        T *= SWZ(P, SWZ_BCAST15);

        if (T < 1e-6f) done = true;        // residual depth <= 1e-6 * 57.4
    }

    depth_acc += SWZ(depth_acc, SWZ_XOR(1));
    depth_acc += SWZ(depth_acc, SWZ_XOR(2));
    depth_acc += SWZ(depth_acc, SWZ_XOR(4));
    depth_acc += SWZ(depth_acc, SWZ_XOR(8));
    if (sub == 0) depth_out[ray] = depth_acc;
}

extern "C" void kernel_launch(void* const* d_in, const int* in_sizes, int n_in,
                              void* d_out, int out_size, void* d_ws, size_t ws_size,
                              hipStream_t stream) {
    (void)in_sizes; (void)n_in; (void)ws_size; (void)out_size;
    const float* rays_o = (const float*)d_in[0];
    const float* rays_d = (const float*)d_in[1];
    const float* voxel  = (const float*)d_in[2];
    float* out = (float*)d_out;
    float4* quad = (float4*)d_ws;   // 640000 * 16B = 10.24 MB (ws is 256 MB)

    // numpy constant chain in float32: step == 0.2f
    float rngz  = 5.4f - (-1.0f);
    float prod  = (80.0f * 80.0f) * rngz;
    float ratio = prod / 640000.0f;
    float stepf = (float)(0.5 * pow((double)ratio, 1.0 / 3.0));
    float delta = stepf * 286.0f - stepf * 285.0f;

    pack_quad_kernel<<<(N_CELLS + 255) / 256, 256, 0, stream>>>(voxel, quad);
    nerf_depth_kernel<<<N_RAYS / 16, 256, 0, stream>>>(rays_o, rays_d, quad, out, stepf, delta);
}

// Round 5
// 33.752 us; speedup vs baseline: 1.0682x; 1.0682x over previous
//
#include <hip/hip_runtime.h>
#include <math.h>

#define N_RAYS 86400
#define N_SAMP 287
#define GRP_W  16          // lanes per ray (4 rays per wave)
#define N_CHUNK 18         // ceil(287/16)
#define LOG2E 1.4426950408889634f

// DPP row_shr:N prefix-shift within the 16-lane row; lanes below the row edge
// read `old` = 1.0f (multiplicative identity).
#define ROW_SHR_OLD1(x, N)                                                   \
    __int_as_float(__builtin_amdgcn_update_dpp(                              \
        0x3f800000 /*1.0f*/, __float_as_int(x), 0x110 | (N), 0xF, 0xF, false))

// ds_swizzle BitMode: new_lane = ((lane & and) | or) ^ xor  (per 32-lane half)
#define SWZ(x, pat) __int_as_float(__builtin_amdgcn_ds_swizzle(__float_as_int(x), (pat)))
#define SWZ_BCAST15 0x1F0   // lane 15 of each 16-group
#define SWZ_XOR(m)  (((m) << 10) | 0x1F)

struct PS {   // pipeline stage state for one chunk
    float z, fx, fy, fz;
    float v000, v001, v010, v011, v100, v101, v110, v111;
    bool  inb;
};

__global__ __launch_bounds__(256) void nerf_depth_kernel(
    const float* __restrict__ rays_o,
    const float* __restrict__ rays_d,
    const float* __restrict__ voxel,
    float* __restrict__ depth_out,
    float stepf, float delta)
{
    const int lane = threadIdx.x & 63;
    const int sub  = lane & (GRP_W - 1);
    const int grp  = lane >> 4;
    const int wave = (blockIdx.x * blockDim.x + threadIdx.x) >> 6;
    const int ray  = wave * 4 + grp;         // 86400 = 4 * 21600, exact

    const float ox = rays_o[3*ray+0], oy = rays_o[3*ray+1], oz = rays_o[3*ray+2];
    const float dx = rays_d[3*ray+0], dy = rays_d[3*ray+1], dz = rays_d[3*ray+2];

    const float cx1 = 199.0f / 80.0f;                  const float cx0 = 40.0f * cx1;
    const float cz1 = 15.0f / (5.4f - (-1.0f));        const float cz0 = 1.0f * cz1;
    const float negdelta = -delta;

    // ---- conservative analytic exit bound (slab method), in sample units ----
    // For each axis: one of (hi-o)*inv, (lo-o)*inv is the positive crossing
    // (origin is strictly inside); fmax picks it, handles d==0 (inf) correctly.
    {
    }
    float invx = 1.0f / __fmul_rn(dx, stepf);
    float invy = 1.0f / __fmul_rn(dy, stepf);
    float invz = 1.0f / __fmul_rn(dz, stepf);
    float tx = fmaxf((40.0f - ox) * invx, (-40.0f - ox) * invx);
    float ty = fmaxf((40.0f - oy) * invy, (-40.0f - oy) * invy);
    float tz = fmaxf((5.4f - oz) * invz, (-1.0f - oz) * invz);
    float te = fminf(fminf(fminf(tx, ty), tz), 300.0f);
    int s_stop = (int)te + 2;                       // +2 sample guard; mask is authoritative
    const int nch = min(N_CHUNK, (s_stop >> 4) + 1);  // group-uniform chunk bound

    auto stageA = [&](int c) -> PS {
        PS p;
        const int s = c * GRP_W + sub;
        p.z = __fmul_rn(stepf, (float)s);
        // bit-exact vs numpy: separate mul + add, strict compares
        const float px = __fadd_rn(ox, __fmul_rn(dx, p.z));
        const float py = __fadd_rn(oy, __fmul_rn(dy, p.z));
        const float pz = __fadd_rn(oz, __fmul_rn(dz, p.z));
        const bool inside = !((fmaxf(fabsf(px), fabsf(py)) > 40.0f) |
                              (pz < -1.0f) | (pz > 5.4f));
        p.inb = inside && (s < N_SAMP);
        float ix = fminf(fmaxf(__builtin_fmaf(px, cx1, cx0), 0.0f), 199.0f);
        float iy = fminf(fmaxf(__builtin_fmaf(py, cx1, cx0), 0.0f), 199.0f);
        float iz = fminf(fmaxf(__builtin_fmaf(pz, cz1, cz0), 0.0f), 15.0f);
        int x0 = min((int)ix, 198);
        int y0 = min((int)iy, 198);
        int z0 = min((int)iz, 14);
        p.fx = ix - (float)x0;
        p.fy = iy - (float)y0;
        p.fz = iz - (float)z0;
        const int cell = (x0 * 200 + y0) * 16 + z0;
        // 8 unconditional loads (clamped addresses are always valid); issued
        // here, consumed one pipeline stage later
        p.v000 = voxel[cell];        p.v001 = voxel[cell + 1];
        p.v010 = voxel[cell + 16];   p.v011 = voxel[cell + 17];
        p.v100 = voxel[cell + 3200]; p.v101 = voxel[cell + 3201];
        p.v110 = voxel[cell + 3216]; p.v111 = voxel[cell + 3217];
        return p;
    };

    float T = 1.0f;
    float depth_acc = 0.0f;

    PS cur = stageA(0);
    int c = 0;
    while (true) {
        PS nxt = stageA(c + 1);     // issue next chunk's loads under this chunk's math

        float c00 = cur.v000 + cur.fz * (cur.v001 - cur.v000);
        float c01 = cur.v010 + cur.fz * (cur.v011 - cur.v010);
        float c10 = cur.v100 + cur.fz * (cur.v101 - cur.v100);
        float c11 = cur.v110 + cur.fz * (cur.v111 - cur.v110);
        float c0  = c00 + cur.fy * (c01 - c00);
        float c1  = c10 + cur.fy * (c11 - c10);
        float d   = c0  + cur.fx * (c1  - c0);
        // alpha = 1 - exp(-delta*softplus(d)) = 1 - 2^(-delta*log2(1+e^d))
        float e2 = exp2f(d * LOG2E);
        float lg = __log2f(1.0f + e2);
        float alpha = 1.0f - exp2f(negdelta * lg);
        alpha = cur.inb ? alpha : 0.0f;

        float g = fmaxf(1.0f - alpha, 1e-10f);

        // 16-lane inclusive prefix product via DPP row_shr
        float P = g;
        P *= ROW_SHR_OLD1(P, 1);
        P *= ROW_SHR_OLD1(P, 2);
        P *= ROW_SHR_OLD1(P, 4);
        P *= ROW_SHR_OLD1(P, 8);
        float E = ROW_SHR_OLD1(P, 1);      // exclusive prefix (lane0 -> 1.0)

        depth_acc = __builtin_fmaf(alpha * cur.z, T * E, depth_acc);
        T *= SWZ(P, SWZ_BCAST15);          // chunk product -> all 16 lanes

        ++c;
        // group-uniform exits: past conservative bound, or transmittance dead
        // (residual depth <= 1e-6 * 57.4 << threshold)
        bool done = (c >= nch) | (T < 1e-6f);
        if (__all(done)) break;
        cur = nxt;
    }

    // sum the 16 per-lane partials
    depth_acc += SWZ(depth_acc, SWZ_XOR(1));
    depth_acc += SWZ(depth_acc, SWZ_XOR(2));
    depth_acc += SWZ(depth_acc, SWZ_XOR(4));
    depth_acc += SWZ(depth_acc, SWZ_XOR(8));
    if (sub == 0) depth_out[ray] = depth_acc;
}

extern "C" void kernel_launch(void* const* d_in, const int* in_sizes, int n_in,
                              void* d_out, int out_size, void* d_ws, size_t ws_size,
                              hipStream_t stream) {
    (void)in_sizes; (void)n_in; (void)d_ws; (void)ws_size; (void)out_size;
    const float* rays_o = (const float*)d_in[0];
    const float* rays_d = (const float*)d_in[1];
    const float* voxel  = (const float*)d_in[2];
    float* out = (float*)d_out;

    // numpy constant chain in float32: step == 0.2f
    float rngz  = 5.4f - (-1.0f);
    float prod  = (80.0f * 80.0f) * rngz;
    float ratio = prod / 640000.0f;
    float stepf = (float)(0.5 * pow((double)ratio, 1.0 / 3.0));
    float delta = stepf * 286.0f - stepf * 285.0f;

    // 4 rays/wave, 4 waves/block => 16 rays/block; 86400/16 = 5400 blocks
    nerf_depth_kernel<<<N_RAYS / 16, 256, 0, stream>>>(rays_o, rays_d, voxel, out, stepf, delta);
}